// Round 7
// baseline (889.990 us; speedup 1.0000x reference)
//
#include <hip/hip_runtime.h>
#include <hip/hip_bf16.h>
#include <cmath>

#define T_DIM 2048
#define C_DIM 2048
#define NH    32
#define SS    64
#define NC    32    // chunks
#define CL    64    // chunk length

typedef unsigned short ushort_t;
typedef __attribute__((ext_vector_type(8))) short bf16x8;
typedef __attribute__((ext_vector_type(4))) float f32x4;

__device__ __forceinline__ ushort_t f2bf(float v) {
    union { __hip_bfloat16 b; ushort_t u; } cv;
    cv.b = __float2bfloat16(v);
    return cv.u;
}

__device__ __forceinline__ void gload_lds16(const void* g, void* l) {
    __builtin_amdgcn_global_load_lds((const __attribute__((address_space(1))) void*)g,
                                     (__attribute__((address_space(3))) void*)l,
                                     16, 0, 0);
}

// ---------------------------------------------------------------------------
// Weight cast + transpose: W[K,N] fp32 -> WT[NT,K] bf16 (rows >= N zero-padded)
// ---------------------------------------------------------------------------
__global__ __launch_bounds__(256)
void castT_kernel(const float* __restrict__ W, ushort_t* __restrict__ WT,
                  int K, int N) {
    __shared__ float t[32][33];
    int n0 = blockIdx.x * 32, k0 = blockIdx.y * 32;
    int tx = threadIdx.x & 31, ty = threadIdx.x >> 5;   // 32 x 8
    #pragma unroll
    for (int i = 0; i < 4; ++i) {
        int k = ty + i * 8;
        float v = 0.f;
        if (n0 + tx < N) v = W[(size_t)(k0 + k) * N + n0 + tx];
        t[k][tx] = v;
    }
    __syncthreads();
    #pragma unroll
    for (int i = 0; i < 4; ++i) {
        int n = ty + i * 8;
        WT[(size_t)(n0 + n) * K + k0 + tx] = f2bf(t[tx][n]);
    }
}

// ---------------------------------------------------------------------------
// token-shift prep: sx = (ns?0:prev) - x (fp32) ; xxxb = bf16(x + sx*tmx)
// ---------------------------------------------------------------------------
__global__ __launch_bounds__(256)
void prep_kernel(const float* __restrict__ x, const float* __restrict__ state,
                 const unsigned char* __restrict__ ns,
                 const float* __restrict__ tmx,
                 float* __restrict__ sx, ushort_t* __restrict__ xxxb) {
    int i4 = blockIdx.x * 256 + threadIdx.x;
    if (i4 >= T_DIM * C_DIM / 4) return;
    int idx = i4 * 4;
    int t = idx >> 11;
    int c = idx & 2047;
    float4 xv = *(const float4*)(x + idx);
    float4 prev;
    if (ns[t]) prev = make_float4(0.f, 0.f, 0.f, 0.f);
    else if (t == 0) prev = *(const float4*)(state + c);
    else prev = *(const float4*)(x + idx - C_DIM);
    float4 tm = *(const float4*)(tmx + c);
    float4 s4;
    s4.x = prev.x - xv.x;  s4.y = prev.y - xv.y;
    s4.z = prev.z - xv.z;  s4.w = prev.w - xv.w;
    *(float4*)(sx + idx) = s4;
    ushort4 xb;
    xb.x = f2bf(xv.x + s4.x * tm.x);
    xb.y = f2bf(xv.y + s4.y * tm.y);
    xb.z = f2bf(xv.z + s4.z * tm.z);
    xb.w = f2bf(xv.w + s4.w * tm.w);
    *(ushort4*)(xxxb + idx) = xb;
}

// ---------------------------------------------------------------------------
// bf16 MFMA GEMM: C[M,N] = epi(A[M,K(lda)] @ BT[N,K]^T)
// BM=BN=128, BK=32, 256 threads (4 waves, 2x2 of 64x64), 16x16x32 MFMA.
// EPI: 0 none(f32) 1 tanh(f32) 2 sigmoid(f32) 3 +bias(f32) 4 tanh(bf16)
// ---------------------------------------------------------------------------
template<int EPI>
__global__ __launch_bounds__(256)
void gemm_mfma(const ushort_t* __restrict__ A, int lda,
               const ushort_t* __restrict__ BT,
               const float* __restrict__ bias,
               float* __restrict__ Cf, ushort_t* __restrict__ Cb,
               int ldc, int K) {
    __shared__ ushort_t As[128 * 32];
    __shared__ ushort_t Bs[128 * 32];
    int tid = threadIdx.x;
    int wave = tid >> 6, lane = tid & 63;
    int m0 = blockIdx.y * 128, n0 = blockIdx.x * 128;
    int wm = wave >> 1, wn = wave & 1;

    f32x4 acc[4][4] = {};

    int srow0 = wave * 16 + (lane >> 2);   // staging row within 64-row group
    int schunk = lane & 3;                 // 16B chunk slot 0..3

    for (int k0 = 0; k0 < K; k0 += 32) {
        #pragma unroll
        for (int j = 0; j < 2; ++j) {
            int row = j * 64 + srow0;
            int gch = schunk ^ (row & 3);  // swizzled global chunk
            gload_lds16(A + (size_t)(m0 + row) * lda + k0 + gch * 8,
                        As + row * 32 + schunk * 8);
            gload_lds16(BT + (size_t)(n0 + row) * K + k0 + gch * 8,
                        Bs + row * 32 + schunk * 8);
        }
        __syncthreads();

        int fr = lane & 15;
        int fc = lane >> 4;                // logical k-chunk 0..3
        bf16x8 af[4], bfr[4];
        #pragma unroll
        for (int mi = 0; mi < 4; ++mi) {
            int r = wm * 64 + mi * 16 + fr;
            af[mi] = *(const bf16x8*)(As + r * 32 + ((fc ^ (r & 3)) * 8));
        }
        #pragma unroll
        for (int ni = 0; ni < 4; ++ni) {
            int c = wn * 64 + ni * 16 + fr;
            bfr[ni] = *(const bf16x8*)(Bs + c * 32 + ((fc ^ (c & 3)) * 8));
        }
        #pragma unroll
        for (int mi = 0; mi < 4; ++mi)
            #pragma unroll
            for (int ni = 0; ni < 4; ++ni)
                acc[mi][ni] = __builtin_amdgcn_mfma_f32_16x16x32_bf16(
                    af[mi], bfr[ni], acc[mi][ni], 0, 0, 0);
        __syncthreads();
    }

    // epilogue: C/D layout col=lane&15, row=(lane>>4)*4+reg
    int colin = lane & 15;
    int rquad = lane >> 4;
    #pragma unroll
    for (int mi = 0; mi < 4; ++mi) {
        #pragma unroll
        for (int reg = 0; reg < 4; ++reg) {
            int row = m0 + wm * 64 + mi * 16 + rquad * 4 + reg;
            #pragma unroll
            for (int ni = 0; ni < 4; ++ni) {
                int col = n0 + wn * 64 + ni * 16 + colin;
                float v = acc[mi][ni][reg];
                if (EPI == 1) v = tanhf(v);
                else if (EPI == 2) v = 1.f / (1.f + __expf(-v));
                else if (EPI == 3) v += bias[col];
                else if (EPI == 4) v = tanhf(v);
                if (EPI == 4) Cb[(size_t)row * ldc + col] = f2bf(v);
                else          Cf[(size_t)row * ldc + col] = v;
            }
        }
    }
}

// ---------------------------------------------------------------------------
// LoRA combine (2-D tiled): block = 4 tokens x 256 columns.
// Grid (T/4, C/256) = 4096 blocks -> 16 blocks/CU (round-6's 512-block grid
// gave 8 waves/CU, latency-bound at 17% VALUBusy).  W2 reuse factor 4.
// ---------------------------------------------------------------------------
#define TT 4
__global__ __launch_bounds__(256)
void maa_combine(const float* __restrict__ x, const float* __restrict__ sx,
                 const float* __restrict__ mtl, const float* __restrict__ W2,
                 const float* __restrict__ tmr, const float* __restrict__ tmk,
                 const float* __restrict__ tmv, const float* __restrict__ tmw,
                 const float* __restrict__ tmg,
                 ushort_t* __restrict__ xr, ushort_t* __restrict__ xk,
                 ushort_t* __restrict__ xv, ushort_t* __restrict__ xw,
                 ushort_t* __restrict__ xg) {
    int t0 = blockIdx.x * TT;
    int c  = blockIdx.y * 256 + threadIdx.x;
    __shared__ float ml[TT][160];
    for (int i = threadIdx.x; i < TT * 160; i += 256) {
        int tt = i / 160, l = i - tt * 160;
        ml[tt][l] = mtl[(size_t)(t0 + tt) * 256 + l];
    }
    __syncthreads();

    float acc[5][TT] = {};
    #pragma unroll 2
    for (int l0 = 0; l0 < 32; l0 += 4) {
        #pragma unroll
        for (int br = 0; br < 5; ++br) {
            const float* w = W2 + (size_t)(br * 32 + l0) * C_DIM + c;
            float w0 = w[0];
            float w1 = w[C_DIM];
            float w2 = w[2 * C_DIM];
            float w3 = w[3 * C_DIM];
            #pragma unroll
            for (int tt = 0; tt < TT; ++tt) {
                float4 m4 = *(const float4*)&ml[tt][br * 32 + l0];
                float a = acc[br][tt];
                a = fmaf(m4.x, w0, a);
                a = fmaf(m4.y, w1, a);
                a = fmaf(m4.z, w2, a);
                a = fmaf(m4.w, w3, a);
                acc[br][tt] = a;
            }
        }
    }
    float t0r = tmr[c], t1r = tmk[c], t2r = tmv[c], t3r = tmw[c], t4r = tmg[c];
    #pragma unroll
    for (int tt = 0; tt < TT; ++tt) {
        size_t idx = (size_t)(t0 + tt) * C_DIM + c;
        float xval = x[idx], sxv = sx[idx];
        xr[idx] = f2bf(xval + sxv * (t0r + acc[0][tt]));
        xk[idx] = f2bf(xval + sxv * (t1r + acc[1][tt]));
        xv[idx] = f2bf(xval + sxv * (t2r + acc[2][tt]));
        xw[idx] = f2bf(xval + sxv * (t3r + acc[3][tt]));
        xg[idx] = f2bf(xval + sxv * (t4r + acc[4][tt]));
    }
}

// ---------------------------------------------------------------------------
// Chunked scan pass 1: per (head, chunk): P[k]=prod ew', U = chunk-local scan.
// ---------------------------------------------------------------------------
__global__ __launch_bounds__(64)
void scan_pass1(const float* __restrict__ k0, const float* __restrict__ v0,
                const float* __restrict__ dec, const unsigned char* __restrict__ ns,
                float* __restrict__ U, float* __restrict__ P) {
    int h = blockIdx.x, c = blockIdx.y, v = threadIdx.x;
    int hk = h >> 2;
    float u[64];
    #pragma unroll
    for (int k = 0; k < 64; ++k) u[k] = 0.f;
    float pk = 1.f;
    __shared__ float ew_s[64], kk_s[64];
    for (int i = 0; i < CL; ++i) {
        int t = c * CL + i;
        float dv = dec[(size_t)t * 2048 + h * 64 + v];
        float lw = fmaxf(-__expf(dv), -5.f);
        float ew = __expf(lw);
        float ewp = ns[t] ? 0.f : ew;
        ew_s[v] = ewp;
        kk_s[v] = k0[(size_t)t * 512 + hk * 64 + v] * (1.f - ew);
        __syncthreads();
        float vv = v0[(size_t)t * 512 + hk * 64 + v];
        pk *= ewp;
        #pragma unroll
        for (int k = 0; k < 64; ++k)
            u[k] = fmaf(u[k], ew_s[k], kk_s[k] * vv);
        __syncthreads();
    }
    size_t base = ((size_t)h * NC + c) * 4096;
    #pragma unroll
    for (int k = 0; k < 64; ++k) U[base + k * 64 + v] = u[k];
    P[((size_t)h * NC + c) * 64 + v] = pk;
}

// ---------------------------------------------------------------------------
// Pass 2 (elementwise-parallel): one thread per (h,k,v) state element.
// ---------------------------------------------------------------------------
__global__ __launch_bounds__(256)
void scan_pass2(float* __restrict__ U, const float* __restrict__ P,
                const float* __restrict__ state, float* __restrict__ outstate) {
    int e = blockIdx.x * 256 + threadIdx.x;      // e = h*4096 + k*64 + v
    int h = e >> 12;
    int k = (e >> 6) & 63;
    float s = state[C_DIM + e];
    int rem = e & 4095;
    #pragma unroll 4
    for (int c = 0; c < NC; ++c) {
        size_t ub = ((size_t)h * NC + c) * 4096 + rem;
        float p = P[((size_t)h * NC + c) * 64 + k];
        float u = U[ub];
        U[ub] = s;
        s = fmaf(s, p, u);
    }
    outstate[C_DIM + e] = s;
}

// ---------------------------------------------------------------------------
// Pass 3: replay chunk from start state (stored in U), emit y0b = bf16(o*g).
// ---------------------------------------------------------------------------
__global__ __launch_bounds__(64)
void scan_pass3(const float* __restrict__ r, const float* __restrict__ k0,
                const float* __restrict__ v0, const float* __restrict__ dec,
                const unsigned char* __restrict__ ns,
                const float* __restrict__ Sstarts, const float* __restrict__ g,
                ushort_t* __restrict__ y0b) {
    int h = blockIdx.x, c = blockIdx.y, v = threadIdx.x;
    int hk = h >> 2;
    float s[64];
    size_t base = ((size_t)h * NC + c) * 4096;
    #pragma unroll
    for (int k = 0; k < 64; ++k) s[k] = Sstarts[base + k * 64 + v];
    __shared__ float r_s[64], ew_s[64], kk_s[64];
    for (int i = 0; i < CL; ++i) {
        int t = c * CL + i;
        float dv = dec[(size_t)t * 2048 + h * 64 + v];
        float lw = fmaxf(-__expf(dv), -5.f);
        float ew = __expf(lw);
        ew_s[v] = ns[t] ? 0.f : ew;
        kk_s[v] = k0[(size_t)t * 512 + hk * 64 + v] * (1.f - ew);
        r_s[v]  = r[(size_t)t * 2048 + h * 64 + v];
        __syncthreads();
        float vv = v0[(size_t)t * 512 + hk * 64 + v];
        float o = 0.f;
        #pragma unroll
        for (int k = 0; k < 64; ++k) {
            float sk = fmaf(s[k], ew_s[k], kk_s[k] * vv);
            s[k] = sk;
            o = fmaf(r_s[k], sk, o);
        }
        size_t idx = (size_t)t * 2048 + h * 64 + v;
        y0b[idx] = f2bf(o * g[idx]);
        __syncthreads();
    }
}

__global__ __launch_bounds__(256)
void state0_kernel(const float* __restrict__ x, const int* __restrict__ len,
                   float* __restrict__ outstate) {
    int c = blockIdx.x * 256 + threadIdx.x;
    if (c < C_DIM)
        outstate[c] = x[(size_t)(len[0] - 1) * C_DIM + c];
}

// ---------------------------------------------------------------------------
extern "C" void kernel_launch(void* const* d_in, const int* in_sizes, int n_in,
                              void* d_out, int out_size, void* d_ws, size_t ws_size,
                              hipStream_t stream) {
    const float* x     = (const float*)d_in[0];
    const float* state = (const float*)d_in[1];
    const unsigned char* ns = (const unsigned char*)d_in[2];
    const int*   len   = (const int*)d_in[3];
    const float* tmx   = (const float*)d_in[4];
    const float* tmr   = (const float*)d_in[5];
    const float* tmk   = (const float*)d_in[6];
    const float* tmv   = (const float*)d_in[7];
    const float* tmw   = (const float*)d_in[8];
    const float* tmg   = (const float*)d_in[9];
    const float* W1    = (const float*)d_in[10];   // [C,160]
    const float* W2    = (const float*)d_in[11];   // [5,32,C] fp32 (stays)
    const float* tdec  = (const float*)d_in[12];   // [C]
    const float* Wd1   = (const float*)d_in[13];   // [C,64]
    const float* Wd2   = (const float*)d_in[14];   // [64,C]
    const float* Wq    = (const float*)d_in[15];
    const float* Wk    = (const float*)d_in[16];
    const float* Wv    = (const float*)d_in[17];
    const float* Wg    = (const float*)d_in[18];
    const float* Wo    = (const float*)d_in[19];

    float* out = (float*)d_out;
    float* outstate = out + (size_t)T_DIM * C_DIM;

    // ---- workspace layout (byte offsets; 122 MB total, aliased) ----
    char* wsb = (char*)d_ws;
    const size_t MB = 1024 * 1024;
    float*    sx   = (float*)(wsb + 0);            // 16 MB; later dec
    ushort_t* xxxb = (ushort_t*)(wsb + 16 * MB);   // 8 MB; later y0b
    float*    mtl  = (float*)(wsb + 24 * MB);      // 2 MB region
    ushort_t* tw   = (ushort_t*)(wsb + 24 * MB);   //   tw [T,128] bf16 (after mtl dead)
    float*    P    = (float*)(wsb + 25 * MB);      //   P  [32*32*64] fp32
    ushort_t* xr   = (ushort_t*)(wsb + 26 * MB);   // 8 MB
    ushort_t* xk   = (ushort_t*)(wsb + 34 * MB);   // 8 MB
    ushort_t* xv   = (ushort_t*)(wsb + 42 * MB);   // 8 MB
    ushort_t* xw   = (ushort_t*)(wsb + 50 * MB);   // 8 MB
    ushort_t* xg   = (ushort_t*)(wsb + 58 * MB);   // 8 MB  (ends 66)
    float*    g    = (float*)(wsb + 42 * MB);      // 16 MB over xv,xw
    float*    r    = (float*)(wsb + 66 * MB);      // 16 MB
    float*    k0   = (float*)(wsb + 82 * MB);      // 4 MB
    float*    v0   = (float*)(wsb + 86 * MB);      // 4 MB
    ushort_t* WqT  = (ushort_t*)(wsb + 90 * MB);   // 8 MB
    ushort_t* WkT  = (ushort_t*)(wsb + 98 * MB);   // 2 MB
    ushort_t* WvT  = (ushort_t*)(wsb + 100 * MB);  // 2 MB
    ushort_t* W1T  = (ushort_t*)(wsb + 102 * MB);  // 1 MB  [256,2048]
    ushort_t* Wd1T = (ushort_t*)(wsb + 103 * MB);  // 0.5 MB [128,2048]
    ushort_t* Wd2T = (ushort_t*)(wsb + 103 * MB + 512 * 1024); // 0.25 MB [2048,64]
    ushort_t* WgT  = (ushort_t*)(wsb + 106 * MB);  // 8 MB
    ushort_t* WoT  = (ushort_t*)(wsb + 114 * MB);  // 8 MB (ends 122)
    float*    U    = (float*)(wsb + 90 * MB);      // 16 MB over WqT..WvT (dead by pass1)
    float*    dec  = sx;
    ushort_t* y0b  = xxxb;

    dim3 blk(256);
    int nElem4 = T_DIM * C_DIM / 4;

    // ---- weight cast+transpose ----
    castT_kernel<<<dim3(8, 64), blk, 0, stream>>>(W1, W1T, 2048, 160);     // ->[256,2048]
    castT_kernel<<<dim3(4, 64), blk, 0, stream>>>(Wd1, Wd1T, 2048, 64);    // ->[128,2048]
    castT_kernel<<<dim3(64, 2), blk, 0, stream>>>(Wd2, Wd2T, 64, 2048);    // ->[2048,64]
    castT_kernel<<<dim3(64, 64), blk, 0, stream>>>(Wq, WqT, 2048, 2048);
    castT_kernel<<<dim3(16, 64), blk, 0, stream>>>(Wk, WkT, 2048, 512);
    castT_kernel<<<dim3(16, 64), blk, 0, stream>>>(Wv, WvT, 2048, 512);
    castT_kernel<<<dim3(64, 64), blk, 0, stream>>>(Wg, WgT, 2048, 2048);
    castT_kernel<<<dim3(64, 64), blk, 0, stream>>>(Wo, WoT, 2048, 2048);

    // ---- prep / LoRA ----
    prep_kernel<<<dim3((nElem4 + 255) / 256), blk, 0, stream>>>(x, state, ns, tmx, sx, xxxb);
    gemm_mfma<1><<<dim3(2, 16), blk, 0, stream>>>(xxxb, 2048, W1T, nullptr, mtl, nullptr, 256, 2048);
    maa_combine<<<dim3(T_DIM / TT, C_DIM / 256), blk, 0, stream>>>(
        x, sx, mtl, W2, tmr, tmk, tmv, tmw, tmg, xr, xk, xv, xw, xg);
    // ---- projections (order matters for aliasing) ----
    gemm_mfma<4><<<dim3(1, 16), blk, 0, stream>>>(xw, 2048, Wd1T, nullptr, nullptr, tw, 128, 2048);
    gemm_mfma<0><<<dim3(4, 16), blk, 0, stream>>>(xk, 2048, WkT, nullptr, k0, nullptr, 512, 2048);
    gemm_mfma<0><<<dim3(4, 16), blk, 0, stream>>>(xv, 2048, WvT, nullptr, v0, nullptr, 512, 2048);
    gemm_mfma<0><<<dim3(16, 16), blk, 0, stream>>>(xr, 2048, WqT, nullptr, r, nullptr, 2048, 2048);
    gemm_mfma<3><<<dim3(16, 16), blk, 0, stream>>>(tw, 128, Wd2T, tdec, dec, nullptr, 2048, 64);
    gemm_mfma<2><<<dim3(16, 16), blk, 0, stream>>>(xg, 2048, WgT, nullptr, g, nullptr, 2048, 2048);
    // ---- chunked scan ----
    scan_pass1<<<dim3(NH, NC), dim3(64), 0, stream>>>(k0, v0, dec, ns, U, P);
    scan_pass2<<<dim3(512), blk, 0, stream>>>(U, P, state, outstate);
    scan_pass3<<<dim3(NH, NC), dim3(64), 0, stream>>>(r, k0, v0, dec, ns, U, g, y0b);
    // ---- output ----
    gemm_mfma<0><<<dim3(16, 16), blk, 0, stream>>>(y0b, 2048, WoT, nullptr, out, nullptr, 2048, 2048);
    state0_kernel<<<dim3(8), blk, 0, stream>>>(x, len, outstate);
}

// Round 8
// 734.374 us; speedup vs baseline: 1.2119x; 1.2119x over previous
//
#include <hip/hip_runtime.h>
#include <hip/hip_bf16.h>
#include <cmath>

#define T_DIM 2048
#define C_DIM 2048
#define NH    32
#define SS    64
#define NC    32    // chunks
#define CL    64    // chunk length

typedef unsigned short ushort_t;
typedef __attribute__((ext_vector_type(8))) short bf16x8;
typedef __attribute__((ext_vector_type(4))) float f32x4;

__device__ __forceinline__ ushort_t f2bf(float v) {
    union { __hip_bfloat16 b; ushort_t u; } cv;
    cv.b = __float2bfloat16(v);
    return cv.u;
}

__device__ __forceinline__ void gload_lds16(const void* g, void* l) {
    __builtin_amdgcn_global_load_lds((const __attribute__((address_space(1))) void*)g,
                                     (__attribute__((address_space(3))) void*)l,
                                     16, 0, 0);
}

// ---------------------------------------------------------------------------
// Weight cast + transpose: W[K,N] fp32 -> WT[NT,K] bf16 (rows >= N zero-padded)
// ---------------------------------------------------------------------------
__global__ __launch_bounds__(256)
void castT_kernel(const float* __restrict__ W, ushort_t* __restrict__ WT,
                  int K, int N) {
    __shared__ float t[32][33];
    int n0 = blockIdx.x * 32, k0 = blockIdx.y * 32;
    int tx = threadIdx.x & 31, ty = threadIdx.x >> 5;   // 32 x 8
    #pragma unroll
    for (int i = 0; i < 4; ++i) {
        int k = ty + i * 8;
        float v = 0.f;
        if (n0 + tx < N) v = W[(size_t)(k0 + k) * N + n0 + tx];
        t[k][tx] = v;
    }
    __syncthreads();
    #pragma unroll
    for (int i = 0; i < 4; ++i) {
        int n = ty + i * 8;
        WT[(size_t)(n0 + n) * K + k0 + tx] = f2bf(t[tx][n]);
    }
}

// ---------------------------------------------------------------------------
// token-shift prep: sx = (ns?0:prev) - x (fp32) ; xxxb = bf16(x + sx*tmx)
// ---------------------------------------------------------------------------
__global__ __launch_bounds__(256)
void prep_kernel(const float* __restrict__ x, const float* __restrict__ state,
                 const unsigned char* __restrict__ ns,
                 const float* __restrict__ tmx,
                 float* __restrict__ sx, ushort_t* __restrict__ xxxb) {
    int i4 = blockIdx.x * 256 + threadIdx.x;
    if (i4 >= T_DIM * C_DIM / 4) return;
    int idx = i4 * 4;
    int t = idx >> 11;
    int c = idx & 2047;
    float4 xv = *(const float4*)(x + idx);
    float4 prev;
    if (ns[t]) prev = make_float4(0.f, 0.f, 0.f, 0.f);
    else if (t == 0) prev = *(const float4*)(state + c);
    else prev = *(const float4*)(x + idx - C_DIM);
    float4 tm = *(const float4*)(tmx + c);
    float4 s4;
    s4.x = prev.x - xv.x;  s4.y = prev.y - xv.y;
    s4.z = prev.z - xv.z;  s4.w = prev.w - xv.w;
    *(float4*)(sx + idx) = s4;
    ushort4 xb;
    xb.x = f2bf(xv.x + s4.x * tm.x);
    xb.y = f2bf(xv.y + s4.y * tm.y);
    xb.z = f2bf(xv.z + s4.z * tm.z);
    xb.w = f2bf(xv.w + s4.w * tm.w);
    *(ushort4*)(xxxb + idx) = xb;
}

// ---------------------------------------------------------------------------
// bf16 MFMA GEMM: C[M,N] = epi(A[M,K(lda)] @ BT[N,K]^T)
// BM=BN=128, BK=32, 256 threads (4 waves, 2x2 of 64x64), 16x16x32 MFMA.
// EPI: 0 none(f32) 1 tanh(f32) 2 sigmoid(f32) 3 +bias(f32) 4 tanh(bf16)
// ---------------------------------------------------------------------------
template<int EPI>
__global__ __launch_bounds__(256)
void gemm_mfma(const ushort_t* __restrict__ A, int lda,
               const ushort_t* __restrict__ BT,
               const float* __restrict__ bias,
               float* __restrict__ Cf, ushort_t* __restrict__ Cb,
               int ldc, int K) {
    __shared__ ushort_t As[128 * 32];
    __shared__ ushort_t Bs[128 * 32];
    int tid = threadIdx.x;
    int wave = tid >> 6, lane = tid & 63;
    int m0 = blockIdx.y * 128, n0 = blockIdx.x * 128;
    int wm = wave >> 1, wn = wave & 1;

    f32x4 acc[4][4] = {};

    int srow0 = wave * 16 + (lane >> 2);   // staging row within 64-row group
    int schunk = lane & 3;                 // 16B chunk slot 0..3

    for (int k0 = 0; k0 < K; k0 += 32) {
        #pragma unroll
        for (int j = 0; j < 2; ++j) {
            int row = j * 64 + srow0;
            int gch = schunk ^ (row & 3);  // swizzled global chunk
            gload_lds16(A + (size_t)(m0 + row) * lda + k0 + gch * 8,
                        As + row * 32 + schunk * 8);
            gload_lds16(BT + (size_t)(n0 + row) * K + k0 + gch * 8,
                        Bs + row * 32 + schunk * 8);
        }
        __syncthreads();

        int fr = lane & 15;
        int fc = lane >> 4;                // logical k-chunk 0..3
        bf16x8 af[4], bfr[4];
        #pragma unroll
        for (int mi = 0; mi < 4; ++mi) {
            int r = wm * 64 + mi * 16 + fr;
            af[mi] = *(const bf16x8*)(As + r * 32 + ((fc ^ (r & 3)) * 8));
        }
        #pragma unroll
        for (int ni = 0; ni < 4; ++ni) {
            int c = wn * 64 + ni * 16 + fr;
            bfr[ni] = *(const bf16x8*)(Bs + c * 32 + ((fc ^ (c & 3)) * 8));
        }
        #pragma unroll
        for (int mi = 0; mi < 4; ++mi)
            #pragma unroll
            for (int ni = 0; ni < 4; ++ni)
                acc[mi][ni] = __builtin_amdgcn_mfma_f32_16x16x32_bf16(
                    af[mi], bfr[ni], acc[mi][ni], 0, 0, 0);
        __syncthreads();
    }

    // epilogue: C/D layout col=lane&15, row=(lane>>4)*4+reg
    int colin = lane & 15;
    int rquad = lane >> 4;
    #pragma unroll
    for (int mi = 0; mi < 4; ++mi) {
        #pragma unroll
        for (int reg = 0; reg < 4; ++reg) {
            int row = m0 + wm * 64 + mi * 16 + rquad * 4 + reg;
            #pragma unroll
            for (int ni = 0; ni < 4; ++ni) {
                int col = n0 + wn * 64 + ni * 16 + colin;
                float v = acc[mi][ni][reg];
                if (EPI == 1) v = tanhf(v);
                else if (EPI == 2) v = 1.f / (1.f + __expf(-v));
                else if (EPI == 3) v += bias[col];
                else if (EPI == 4) v = tanhf(v);
                if (EPI == 4) Cb[(size_t)row * ldc + col] = f2bf(v);
                else          Cf[(size_t)row * ldc + col] = v;
            }
        }
    }
}

// ---------------------------------------------------------------------------
// LoRA-combine as batched MFMA GEMM.  blockIdx.z = branch br (0..4).
// m[br] = mtlb[:, br*32 .. br*32+32) @ W2T[br]   (K=32, one MFMA per frag)
// epilogue: dst_br = bf16(x + sx*(tm_br + m))
// Replaces the scalar maa_combine (r4-r7: 130-190 us, latency/L2-bound).
// ---------------------------------------------------------------------------
__global__ __launch_bounds__(256)
void maa_gemm(const ushort_t* __restrict__ mtlb,      // [T,256] bf16 tanh
              const ushort_t* __restrict__ W2Tall,    // [5][C][32] bf16
              const float* __restrict__ x, const float* __restrict__ sx,
              const float* __restrict__ tmr, const float* __restrict__ tmk,
              const float* __restrict__ tmv, const float* __restrict__ tmw,
              const float* __restrict__ tmg,
              ushort_t* __restrict__ xr, ushort_t* __restrict__ xk,
              ushort_t* __restrict__ xv, ushort_t* __restrict__ xw,
              ushort_t* __restrict__ xg) {
    int br = blockIdx.z;
    const ushort_t* BT = W2Tall + (size_t)br * C_DIM * 32;
    const float* tm; ushort_t* dst;
    if      (br == 0) { tm = tmr; dst = xr; }
    else if (br == 1) { tm = tmk; dst = xk; }
    else if (br == 2) { tm = tmv; dst = xv; }
    else if (br == 3) { tm = tmw; dst = xw; }
    else              { tm = tmg; dst = xg; }

    __shared__ ushort_t As[128 * 32];
    __shared__ ushort_t Bs[128 * 32];
    int tid = threadIdx.x;
    int wave = tid >> 6, lane = tid & 63;
    int m0 = blockIdx.y * 128, n0 = blockIdx.x * 128;
    int wm = wave >> 1, wn = wave & 1;
    int srow0 = wave * 16 + (lane >> 2);
    int schunk = lane & 3;

    #pragma unroll
    for (int j = 0; j < 2; ++j) {
        int row = j * 64 + srow0;
        int gch = schunk ^ (row & 3);
        gload_lds16(mtlb + (size_t)(m0 + row) * 256 + br * 32 + gch * 8,
                    As + row * 32 + schunk * 8);
        gload_lds16(BT + (size_t)(n0 + row) * 32 + gch * 8,
                    Bs + row * 32 + schunk * 8);
    }
    __syncthreads();

    int fr = lane & 15;
    int fc = lane >> 4;
    f32x4 acc[4][4] = {};
    bf16x8 af[4], bfr[4];
    #pragma unroll
    for (int mi = 0; mi < 4; ++mi) {
        int r = wm * 64 + mi * 16 + fr;
        af[mi] = *(const bf16x8*)(As + r * 32 + ((fc ^ (r & 3)) * 8));
    }
    #pragma unroll
    for (int ni = 0; ni < 4; ++ni) {
        int c = wn * 64 + ni * 16 + fr;
        bfr[ni] = *(const bf16x8*)(Bs + c * 32 + ((fc ^ (c & 3)) * 8));
    }
    #pragma unroll
    for (int mi = 0; mi < 4; ++mi)
        #pragma unroll
        for (int ni = 0; ni < 4; ++ni)
            acc[mi][ni] = __builtin_amdgcn_mfma_f32_16x16x32_bf16(
                af[mi], bfr[ni], acc[mi][ni], 0, 0, 0);

    int colin = lane & 15;
    int rquad = lane >> 4;
    #pragma unroll
    for (int mi = 0; mi < 4; ++mi) {
        #pragma unroll
        for (int reg = 0; reg < 4; ++reg) {
            int row = m0 + wm * 64 + mi * 16 + rquad * 4 + reg;
            #pragma unroll
            for (int ni = 0; ni < 4; ++ni) {
                int col = n0 + wn * 64 + ni * 16 + colin;
                size_t idx = (size_t)row * C_DIM + col;
                float m = acc[mi][ni][reg];
                dst[idx] = f2bf(x[idx] + sx[idx] * (tm[col] + m));
            }
        }
    }
}

// ---------------------------------------------------------------------------
// Chunked scan pass 1: per (head, chunk): P[k]=prod ew', U = chunk-local scan.
// ---------------------------------------------------------------------------
__global__ __launch_bounds__(64)
void scan_pass1(const float* __restrict__ k0, const float* __restrict__ v0,
                const float* __restrict__ dec, const unsigned char* __restrict__ ns,
                float* __restrict__ U, float* __restrict__ P) {
    int h = blockIdx.x, c = blockIdx.y, v = threadIdx.x;
    int hk = h >> 2;
    float u[64];
    #pragma unroll
    for (int k = 0; k < 64; ++k) u[k] = 0.f;
    float pk = 1.f;
    __shared__ float ew_s[64], kk_s[64];
    for (int i = 0; i < CL; ++i) {
        int t = c * CL + i;
        float dv = dec[(size_t)t * 2048 + h * 64 + v];
        float lw = fmaxf(-__expf(dv), -5.f);
        float ew = __expf(lw);
        float ewp = ns[t] ? 0.f : ew;
        ew_s[v] = ewp;
        kk_s[v] = k0[(size_t)t * 512 + hk * 64 + v] * (1.f - ew);
        __syncthreads();
        float vv = v0[(size_t)t * 512 + hk * 64 + v];
        pk *= ewp;
        #pragma unroll
        for (int k = 0; k < 64; ++k)
            u[k] = fmaf(u[k], ew_s[k], kk_s[k] * vv);
        __syncthreads();
    }
    size_t base = ((size_t)h * NC + c) * 4096;
    #pragma unroll
    for (int k = 0; k < 64; ++k) U[base + k * 64 + v] = u[k];
    P[((size_t)h * NC + c) * 64 + v] = pk;
}

// ---------------------------------------------------------------------------
// Pass 2 (elementwise-parallel): one thread per (h,k,v) state element.
// ---------------------------------------------------------------------------
__global__ __launch_bounds__(256)
void scan_pass2(float* __restrict__ U, const float* __restrict__ P,
                const float* __restrict__ state, float* __restrict__ outstate) {
    int e = blockIdx.x * 256 + threadIdx.x;      // e = h*4096 + k*64 + v
    int h = e >> 12;
    int k = (e >> 6) & 63;
    float s = state[C_DIM + e];
    int rem = e & 4095;
    #pragma unroll 4
    for (int c = 0; c < NC; ++c) {
        size_t ub = ((size_t)h * NC + c) * 4096 + rem;
        float p = P[((size_t)h * NC + c) * 64 + k];
        float u = U[ub];
        U[ub] = s;
        s = fmaf(s, p, u);
    }
    outstate[C_DIM + e] = s;
}

// ---------------------------------------------------------------------------
// Pass 3: replay chunk from start state (stored in U), emit y0b = bf16(o*g).
// ---------------------------------------------------------------------------
__global__ __launch_bounds__(64)
void scan_pass3(const float* __restrict__ r, const float* __restrict__ k0,
                const float* __restrict__ v0, const float* __restrict__ dec,
                const unsigned char* __restrict__ ns,
                const float* __restrict__ Sstarts, const float* __restrict__ g,
                ushort_t* __restrict__ y0b) {
    int h = blockIdx.x, c = blockIdx.y, v = threadIdx.x;
    int hk = h >> 2;
    float s[64];
    size_t base = ((size_t)h * NC + c) * 4096;
    #pragma unroll
    for (int k = 0; k < 64; ++k) s[k] = Sstarts[base + k * 64 + v];
    __shared__ float r_s[64], ew_s[64], kk_s[64];
    for (int i = 0; i < CL; ++i) {
        int t = c * CL + i;
        float dv = dec[(size_t)t * 2048 + h * 64 + v];
        float lw = fmaxf(-__expf(dv), -5.f);
        float ew = __expf(lw);
        ew_s[v] = ns[t] ? 0.f : ew;
        kk_s[v] = k0[(size_t)t * 512 + hk * 64 + v] * (1.f - ew);
        r_s[v]  = r[(size_t)t * 2048 + h * 64 + v];
        __syncthreads();
        float vv = v0[(size_t)t * 512 + hk * 64 + v];
        float o = 0.f;
        #pragma unroll
        for (int k = 0; k < 64; ++k) {
            float sk = fmaf(s[k], ew_s[k], kk_s[k] * vv);
            s[k] = sk;
            o = fmaf(r_s[k], sk, o);
        }
        size_t idx = (size_t)t * 2048 + h * 64 + v;
        y0b[idx] = f2bf(o * g[idx]);
        __syncthreads();
    }
}

__global__ __launch_bounds__(256)
void state0_kernel(const float* __restrict__ x, const int* __restrict__ len,
                   float* __restrict__ outstate) {
    int c = blockIdx.x * 256 + threadIdx.x;
    if (c < C_DIM)
        outstate[c] = x[(size_t)(len[0] - 1) * C_DIM + c];
}

// ---------------------------------------------------------------------------
extern "C" void kernel_launch(void* const* d_in, const int* in_sizes, int n_in,
                              void* d_out, int out_size, void* d_ws, size_t ws_size,
                              hipStream_t stream) {
    const float* x     = (const float*)d_in[0];
    const float* state = (const float*)d_in[1];
    const unsigned char* ns = (const unsigned char*)d_in[2];
    const int*   len   = (const int*)d_in[3];
    const float* tmx   = (const float*)d_in[4];
    const float* tmr   = (const float*)d_in[5];
    const float* tmk   = (const float*)d_in[6];
    const float* tmv   = (const float*)d_in[7];
    const float* tmw   = (const float*)d_in[8];
    const float* tmg   = (const float*)d_in[9];
    const float* W1    = (const float*)d_in[10];   // [C,160]
    const float* W2    = (const float*)d_in[11];   // [5,32,C]
    const float* tdec  = (const float*)d_in[12];   // [C]
    const float* Wd1   = (const float*)d_in[13];   // [C,64]
    const float* Wd2   = (const float*)d_in[14];   // [64,C]
    const float* Wq    = (const float*)d_in[15];
    const float* Wk    = (const float*)d_in[16];
    const float* Wv    = (const float*)d_in[17];
    const float* Wg    = (const float*)d_in[18];
    const float* Wo    = (const float*)d_in[19];

    float* out = (float*)d_out;
    float* outstate = out + (size_t)T_DIM * C_DIM;

    // ---- workspace layout (byte offsets; 122 MB total, aliased) ----
    char* wsb = (char*)d_ws;
    const size_t MB = 1024 * 1024;
    float*    sx   = (float*)(wsb + 0);            // 16 MB; later dec
    ushort_t* xxxb = (ushort_t*)(wsb + 16 * MB);   // 8 MB; later y0b
    ushort_t* mtlb = (ushort_t*)(wsb + 24 * MB);   // 1 MB  [T,256] bf16 tanh
    ushort_t* tw   = (ushort_t*)(wsb + 25 * MB);   // 0.5 MB [T,128] bf16
    float*    P    = (float*)(wsb + 25 * MB + 512 * 1024);  // 256 KB
    ushort_t* xr   = (ushort_t*)(wsb + 26 * MB);   // 8 MB
    ushort_t* xk   = (ushort_t*)(wsb + 34 * MB);   // 8 MB
    ushort_t* xv   = (ushort_t*)(wsb + 42 * MB);   // 8 MB
    ushort_t* xw   = (ushort_t*)(wsb + 50 * MB);   // 8 MB
    ushort_t* xg   = (ushort_t*)(wsb + 58 * MB);   // 8 MB  (ends 66)
    float*    g    = (float*)(wsb + 42 * MB);      // 16 MB over xv,xw
    float*    r    = (float*)(wsb + 66 * MB);      // 16 MB
    float*    k0   = (float*)(wsb + 82 * MB);      // 4 MB
    float*    v0   = (float*)(wsb + 86 * MB);      // 4 MB
    ushort_t* WqT  = (ushort_t*)(wsb + 90 * MB);   // 8 MB
    ushort_t* WkT  = (ushort_t*)(wsb + 98 * MB);   // 2 MB
    ushort_t* WvT  = (ushort_t*)(wsb + 100 * MB);  // 2 MB
    ushort_t* W1T  = (ushort_t*)(wsb + 102 * MB);  // 1 MB  [256,2048]
    ushort_t* Wd1T = (ushort_t*)(wsb + 103 * MB);  // 0.5 MB [128,2048]
    ushort_t* Wd2T = (ushort_t*)(wsb + 103 * MB + 512 * 1024); // 0.25 MB [2048,64]
    ushort_t* W2Tall = (ushort_t*)(wsb + 104 * MB); // 640 KB [5][C][32] (dead gap in U span)
    ushort_t* WgT  = (ushort_t*)(wsb + 106 * MB);  // 8 MB
    ushort_t* WoT  = (ushort_t*)(wsb + 114 * MB);  // 8 MB (ends 122)
    float*    U    = (float*)(wsb + 90 * MB);      // 16 MB over WqT..W2Tall (dead by pass1)
    float*    dec  = sx;
    ushort_t* y0b  = xxxb;

    dim3 blk(256);
    int nElem4 = T_DIM * C_DIM / 4;

    // ---- weight cast+transpose ----
    castT_kernel<<<dim3(8, 64), blk, 0, stream>>>(W1, W1T, 2048, 160);     // ->[256,2048]
    castT_kernel<<<dim3(4, 64), blk, 0, stream>>>(Wd1, Wd1T, 2048, 64);    // ->[128,2048]
    castT_kernel<<<dim3(64, 2), blk, 0, stream>>>(Wd2, Wd2T, 64, 2048);    // ->[2048,64]
    castT_kernel<<<dim3(64, 64), blk, 0, stream>>>(Wq, WqT, 2048, 2048);
    castT_kernel<<<dim3(16, 64), blk, 0, stream>>>(Wk, WkT, 2048, 512);
    castT_kernel<<<dim3(16, 64), blk, 0, stream>>>(Wv, WvT, 2048, 512);
    castT_kernel<<<dim3(64, 64), blk, 0, stream>>>(Wg, WgT, 2048, 2048);
    castT_kernel<<<dim3(64, 64), blk, 0, stream>>>(Wo, WoT, 2048, 2048);
    // W2 branches: [32,C] -> [C,32] bf16
    for (int br = 0; br < 5; ++br)
        castT_kernel<<<dim3(64, 1), blk, 0, stream>>>(
            W2 + (size_t)br * 32 * C_DIM, W2Tall + (size_t)br * C_DIM * 32, 32, 2048);

    // ---- prep / LoRA ----
    prep_kernel<<<dim3((nElem4 + 255) / 256), blk, 0, stream>>>(x, state, ns, tmx, sx, xxxb);
    // mtlb = tanh(xxx @ W1) as bf16, [T,256] (cols 160..255 = tanh(0) = 0)
    gemm_mfma<4><<<dim3(2, 16), blk, 0, stream>>>(xxxb, 2048, W1T, nullptr, nullptr, mtlb, 256, 2048);
    // 5-branch LoRA combine via MFMA, fused epilogue
    maa_gemm<<<dim3(16, 16, 5), blk, 0, stream>>>(mtlb, W2Tall, x, sx,
                                                  tmr, tmk, tmv, tmw, tmg,
                                                  xr, xk, xv, xw, xg);
    // ---- projections (order matters for aliasing) ----
    gemm_mfma<4><<<dim3(1, 16), blk, 0, stream>>>(xw, 2048, Wd1T, nullptr, nullptr, tw, 128, 2048);
    gemm_mfma<0><<<dim3(4, 16), blk, 0, stream>>>(xk, 2048, WkT, nullptr, k0, nullptr, 512, 2048);
    gemm_mfma<0><<<dim3(4, 16), blk, 0, stream>>>(xv, 2048, WvT, nullptr, v0, nullptr, 512, 2048);
    gemm_mfma<0><<<dim3(16, 16), blk, 0, stream>>>(xr, 2048, WqT, nullptr, r, nullptr, 2048, 2048);
    gemm_mfma<3><<<dim3(16, 16), blk, 0, stream>>>(tw, 128, Wd2T, tdec, dec, nullptr, 2048, 64);
    gemm_mfma<2><<<dim3(16, 16), blk, 0, stream>>>(xg, 2048, WgT, nullptr, g, nullptr, 2048, 2048);
    // ---- chunked scan ----
    scan_pass1<<<dim3(NH, NC), dim3(64), 0, stream>>>(k0, v0, dec, ns, U, P);
    scan_pass2<<<dim3(512), blk, 0, stream>>>(U, P, state, outstate);
    scan_pass3<<<dim3(NH, NC), dim3(64), 0, stream>>>(r, k0, v0, dec, ns, U, g, y0b);
    // ---- output ----
    gemm_mfma<0><<<dim3(16, 16), blk, 0, stream>>>(y0b, 2048, WoT, nullptr, out, nullptr, 2048, 2048);
    state0_kernel<<<dim3(8), blk, 0, stream>>>(x, len, outstate);
}

// Round 9
// 678.590 us; speedup vs baseline: 1.3115x; 1.0822x over previous
//
#include <hip/hip_runtime.h>
#include <hip/hip_bf16.h>
#include <cmath>

#define T_DIM 2048
#define C_DIM 2048
#define NH    32
#define SS    64
#define NC    64    // chunks (r9: was 32 -> 2048 waves, 8/CU, halved serial chain)
#define CL    32    // chunk length

typedef unsigned short ushort_t;
typedef __attribute__((ext_vector_type(8))) short bf16x8;
typedef __attribute__((ext_vector_type(4))) float f32x4;

__device__ __forceinline__ ushort_t f2bf(float v) {
    union { __hip_bfloat16 b; ushort_t u; } cv;
    cv.b = __float2bfloat16(v);
    return cv.u;
}

__device__ __forceinline__ void gload_lds16(const void* g, void* l) {
    __builtin_amdgcn_global_load_lds((const __attribute__((address_space(1))) void*)g,
                                     (__attribute__((address_space(3))) void*)l,
                                     16, 0, 0);
}

// ---------------------------------------------------------------------------
// Weight cast + transpose: W[K,N] fp32 -> WT[NT,K] bf16 (rows >= N zero-padded)
// ---------------------------------------------------------------------------
__global__ __launch_bounds__(256)
void castT_kernel(const float* __restrict__ W, ushort_t* __restrict__ WT,
                  int K, int N) {
    __shared__ float t[32][33];
    int n0 = blockIdx.x * 32, k0 = blockIdx.y * 32;
    int tx = threadIdx.x & 31, ty = threadIdx.x >> 5;   // 32 x 8
    #pragma unroll
    for (int i = 0; i < 4; ++i) {
        int k = ty + i * 8;
        float v = 0.f;
        if (n0 + tx < N) v = W[(size_t)(k0 + k) * N + n0 + tx];
        t[k][tx] = v;
    }
    __syncthreads();
    #pragma unroll
    for (int i = 0; i < 4; ++i) {
        int n = ty + i * 8;
        WT[(size_t)(n0 + n) * K + k0 + tx] = f2bf(t[tx][n]);
    }
}

// ---------------------------------------------------------------------------
// token-shift prep: sx = (ns?0:prev) - x (fp32) ; xxxb = bf16(x + sx*tmx)
// ---------------------------------------------------------------------------
__global__ __launch_bounds__(256)
void prep_kernel(const float* __restrict__ x, const float* __restrict__ state,
                 const unsigned char* __restrict__ ns,
                 const float* __restrict__ tmx,
                 float* __restrict__ sx, ushort_t* __restrict__ xxxb) {
    int i4 = blockIdx.x * 256 + threadIdx.x;
    if (i4 >= T_DIM * C_DIM / 4) return;
    int idx = i4 * 4;
    int t = idx >> 11;
    int c = idx & 2047;
    float4 xv = *(const float4*)(x + idx);
    float4 prev;
    if (ns[t]) prev = make_float4(0.f, 0.f, 0.f, 0.f);
    else if (t == 0) prev = *(const float4*)(state + c);
    else prev = *(const float4*)(x + idx - C_DIM);
    float4 tm = *(const float4*)(tmx + c);
    float4 s4;
    s4.x = prev.x - xv.x;  s4.y = prev.y - xv.y;
    s4.z = prev.z - xv.z;  s4.w = prev.w - xv.w;
    *(float4*)(sx + idx) = s4;
    ushort4 xb;
    xb.x = f2bf(xv.x + s4.x * tm.x);
    xb.y = f2bf(xv.y + s4.y * tm.y);
    xb.z = f2bf(xv.z + s4.z * tm.z);
    xb.w = f2bf(xv.w + s4.w * tm.w);
    *(ushort4*)(xxxb + idx) = xb;
}

// ---------------------------------------------------------------------------
// bf16 MFMA GEMM: C[M,N] = epi(A[M,K(lda)] @ BT[N,K]^T)
// BM=BN=128, BK=32, 256 threads (4 waves, 2x2 of 64x64), 16x16x32 MFMA.
// EPI: 0 none(f32) 1 tanh(f32) 2 sigmoid(f32) 3 +bias(f32) 4 tanh(bf16)
// ---------------------------------------------------------------------------
template<int EPI>
__global__ __launch_bounds__(256)
void gemm_mfma(const ushort_t* __restrict__ A, int lda,
               const ushort_t* __restrict__ BT,
               const float* __restrict__ bias,
               float* __restrict__ Cf, ushort_t* __restrict__ Cb,
               int ldc, int K) {
    __shared__ ushort_t As[128 * 32];
    __shared__ ushort_t Bs[128 * 32];
    int tid = threadIdx.x;
    int wave = tid >> 6, lane = tid & 63;
    int m0 = blockIdx.y * 128, n0 = blockIdx.x * 128;
    int wm = wave >> 1, wn = wave & 1;

    f32x4 acc[4][4] = {};

    int srow0 = wave * 16 + (lane >> 2);   // staging row within 64-row group
    int schunk = lane & 3;                 // 16B chunk slot 0..3

    for (int k0 = 0; k0 < K; k0 += 32) {
        #pragma unroll
        for (int j = 0; j < 2; ++j) {
            int row = j * 64 + srow0;
            int gch = schunk ^ (row & 3);  // swizzled global chunk
            gload_lds16(A + (size_t)(m0 + row) * lda + k0 + gch * 8,
                        As + row * 32 + schunk * 8);
            gload_lds16(BT + (size_t)(n0 + row) * K + k0 + gch * 8,
                        Bs + row * 32 + schunk * 8);
        }
        __syncthreads();

        int fr = lane & 15;
        int fc = lane >> 4;                // logical k-chunk 0..3
        bf16x8 af[4], bfr[4];
        #pragma unroll
        for (int mi = 0; mi < 4; ++mi) {
            int r = wm * 64 + mi * 16 + fr;
            af[mi] = *(const bf16x8*)(As + r * 32 + ((fc ^ (r & 3)) * 8));
        }
        #pragma unroll
        for (int ni = 0; ni < 4; ++ni) {
            int c = wn * 64 + ni * 16 + fr;
            bfr[ni] = *(const bf16x8*)(Bs + c * 32 + ((fc ^ (c & 3)) * 8));
        }
        #pragma unroll
        for (int mi = 0; mi < 4; ++mi)
            #pragma unroll
            for (int ni = 0; ni < 4; ++ni)
                acc[mi][ni] = __builtin_amdgcn_mfma_f32_16x16x32_bf16(
                    af[mi], bfr[ni], acc[mi][ni], 0, 0, 0);
        __syncthreads();
    }

    // epilogue: C/D layout col=lane&15, row=(lane>>4)*4+reg
    int colin = lane & 15;
    int rquad = lane >> 4;
    #pragma unroll
    for (int mi = 0; mi < 4; ++mi) {
        #pragma unroll
        for (int reg = 0; reg < 4; ++reg) {
            int row = m0 + wm * 64 + mi * 16 + rquad * 4 + reg;
            #pragma unroll
            for (int ni = 0; ni < 4; ++ni) {
                int col = n0 + wn * 64 + ni * 16 + colin;
                float v = acc[mi][ni][reg];
                if (EPI == 1) v = tanhf(v);
                else if (EPI == 2) v = 1.f / (1.f + __expf(-v));
                else if (EPI == 3) v += bias[col];
                else if (EPI == 4) v = tanhf(v);
                if (EPI == 4) Cb[(size_t)row * ldc + col] = f2bf(v);
                else          Cf[(size_t)row * ldc + col] = v;
            }
        }
    }
}

// ---------------------------------------------------------------------------
// LoRA-combine as batched MFMA GEMM.  blockIdx.z = branch br (0..4).
// ---------------------------------------------------------------------------
__global__ __launch_bounds__(256)
void maa_gemm(const ushort_t* __restrict__ mtlb,      // [T,256] bf16 tanh
              const ushort_t* __restrict__ W2Tall,    // [5][C][32] bf16
              const float* __restrict__ x, const float* __restrict__ sx,
              const float* __restrict__ tmr, const float* __restrict__ tmk,
              const float* __restrict__ tmv, const float* __restrict__ tmw,
              const float* __restrict__ tmg,
              ushort_t* __restrict__ xr, ushort_t* __restrict__ xk,
              ushort_t* __restrict__ xv, ushort_t* __restrict__ xw,
              ushort_t* __restrict__ xg) {
    int br = blockIdx.z;
    const ushort_t* BT = W2Tall + (size_t)br * C_DIM * 32;
    const float* tm; ushort_t* dst;
    if      (br == 0) { tm = tmr; dst = xr; }
    else if (br == 1) { tm = tmk; dst = xk; }
    else if (br == 2) { tm = tmv; dst = xv; }
    else if (br == 3) { tm = tmw; dst = xw; }
    else              { tm = tmg; dst = xg; }

    __shared__ ushort_t As[128 * 32];
    __shared__ ushort_t Bs[128 * 32];
    int tid = threadIdx.x;
    int wave = tid >> 6, lane = tid & 63;
    int m0 = blockIdx.y * 128, n0 = blockIdx.x * 128;
    int wm = wave >> 1, wn = wave & 1;
    int srow0 = wave * 16 + (lane >> 2);
    int schunk = lane & 3;

    #pragma unroll
    for (int j = 0; j < 2; ++j) {
        int row = j * 64 + srow0;
        int gch = schunk ^ (row & 3);
        gload_lds16(mtlb + (size_t)(m0 + row) * 256 + br * 32 + gch * 8,
                    As + row * 32 + schunk * 8);
        gload_lds16(BT + (size_t)(n0 + row) * 32 + gch * 8,
                    Bs + row * 32 + schunk * 8);
    }
    __syncthreads();

    int fr = lane & 15;
    int fc = lane >> 4;
    f32x4 acc[4][4] = {};
    bf16x8 af[4], bfr[4];
    #pragma unroll
    for (int mi = 0; mi < 4; ++mi) {
        int r = wm * 64 + mi * 16 + fr;
        af[mi] = *(const bf16x8*)(As + r * 32 + ((fc ^ (r & 3)) * 8));
    }
    #pragma unroll
    for (int ni = 0; ni < 4; ++ni) {
        int c = wn * 64 + ni * 16 + fr;
        bfr[ni] = *(const bf16x8*)(Bs + c * 32 + ((fc ^ (c & 3)) * 8));
    }
    #pragma unroll
    for (int mi = 0; mi < 4; ++mi)
        #pragma unroll
        for (int ni = 0; ni < 4; ++ni)
            acc[mi][ni] = __builtin_amdgcn_mfma_f32_16x16x32_bf16(
                af[mi], bfr[ni], acc[mi][ni], 0, 0, 0);

    int colin = lane & 15;
    int rquad = lane >> 4;
    #pragma unroll
    for (int mi = 0; mi < 4; ++mi) {
        #pragma unroll
        for (int reg = 0; reg < 4; ++reg) {
            int row = m0 + wm * 64 + mi * 16 + rquad * 4 + reg;
            #pragma unroll
            for (int ni = 0; ni < 4; ++ni) {
                int col = n0 + wn * 64 + ni * 16 + colin;
                size_t idx = (size_t)row * C_DIM + col;
                float m = acc[mi][ni][reg];
                dst[idx] = f2bf(x[idx] + sx[idx] * (tm[col] + m));
            }
        }
    }
}

// ---------------------------------------------------------------------------
// Chunked scan pass 1: per (head, chunk): P[k]=prod ew', U = chunk-local scan.
// ---------------------------------------------------------------------------
__global__ __launch_bounds__(64)
void scan_pass1(const float* __restrict__ k0, const float* __restrict__ v0,
                const float* __restrict__ dec, const unsigned char* __restrict__ ns,
                float* __restrict__ U, float* __restrict__ P) {
    int h = blockIdx.x, c = blockIdx.y, v = threadIdx.x;
    int hk = h >> 2;
    float u[64];
    #pragma unroll
    for (int k = 0; k < 64; ++k) u[k] = 0.f;
    float pk = 1.f;
    __shared__ float ew_s[64], kk_s[64];
    for (int i = 0; i < CL; ++i) {
        int t = c * CL + i;
        float dv = dec[(size_t)t * 2048 + h * 64 + v];
        float lw = fmaxf(-__expf(dv), -5.f);
        float ew = __expf(lw);
        float ewp = ns[t] ? 0.f : ew;
        ew_s[v] = ewp;
        kk_s[v] = k0[(size_t)t * 512 + hk * 64 + v] * (1.f - ew);
        __syncthreads();
        float vv = v0[(size_t)t * 512 + hk * 64 + v];
        pk *= ewp;
        #pragma unroll
        for (int k = 0; k < 64; ++k)
            u[k] = fmaf(u[k], ew_s[k], kk_s[k] * vv);
        __syncthreads();
    }
    size_t base = ((size_t)h * NC + c) * 4096;
    #pragma unroll
    for (int k = 0; k < 64; ++k) U[base + k * 64 + v] = u[k];
    P[((size_t)h * NC + c) * 64 + v] = pk;
}

// ---------------------------------------------------------------------------
// Pass 2 (elementwise-parallel): one thread per (h,k,v) state element.
// ---------------------------------------------------------------------------
__global__ __launch_bounds__(256)
void scan_pass2(float* __restrict__ U, const float* __restrict__ P,
                const float* __restrict__ state, float* __restrict__ outstate) {
    int e = blockIdx.x * 256 + threadIdx.x;      // e = h*4096 + k*64 + v
    int h = e >> 12;
    int k = (e >> 6) & 63;
    float s = state[C_DIM + e];
    int rem = e & 4095;
    #pragma unroll 4
    for (int c = 0; c < NC; ++c) {
        size_t ub = ((size_t)h * NC + c) * 4096 + rem;
        float p = P[((size_t)h * NC + c) * 64 + k];
        float u = U[ub];
        U[ub] = s;
        s = fmaf(s, p, u);
    }
    outstate[C_DIM + e] = s;
}

// ---------------------------------------------------------------------------
// Pass 3: replay chunk from start state (stored in U), emit y0b = bf16(o*g).
// ---------------------------------------------------------------------------
__global__ __launch_bounds__(64)
void scan_pass3(const float* __restrict__ r, const float* __restrict__ k0,
                const float* __restrict__ v0, const float* __restrict__ dec,
                const unsigned char* __restrict__ ns,
                const float* __restrict__ Sstarts, const float* __restrict__ g,
                ushort_t* __restrict__ y0b) {
    int h = blockIdx.x, c = blockIdx.y, v = threadIdx.x;
    int hk = h >> 2;
    float s[64];
    size_t base = ((size_t)h * NC + c) * 4096;
    #pragma unroll
    for (int k = 0; k < 64; ++k) s[k] = Sstarts[base + k * 64 + v];
    __shared__ float r_s[64], ew_s[64], kk_s[64];
    for (int i = 0; i < CL; ++i) {
        int t = c * CL + i;
        float dv = dec[(size_t)t * 2048 + h * 64 + v];
        float lw = fmaxf(-__expf(dv), -5.f);
        float ew = __expf(lw);
        ew_s[v] = ns[t] ? 0.f : ew;
        kk_s[v] = k0[(size_t)t * 512 + hk * 64 + v] * (1.f - ew);
        r_s[v]  = r[(size_t)t * 2048 + h * 64 + v];
        __syncthreads();
        float vv = v0[(size_t)t * 512 + hk * 64 + v];
        float o = 0.f;
        #pragma unroll
        for (int k = 0; k < 64; ++k) {
            float sk = fmaf(s[k], ew_s[k], kk_s[k] * vv);
            s[k] = sk;
            o = fmaf(r_s[k], sk, o);
        }
        size_t idx = (size_t)t * 2048 + h * 64 + v;
        y0b[idx] = f2bf(o * g[idx]);
        __syncthreads();
    }
}

__global__ __launch_bounds__(256)
void state0_kernel(const float* __restrict__ x, const int* __restrict__ len,
                   float* __restrict__ outstate) {
    int c = blockIdx.x * 256 + threadIdx.x;
    if (c < C_DIM)
        outstate[c] = x[(size_t)(len[0] - 1) * C_DIM + c];
}

// ---------------------------------------------------------------------------
extern "C" void kernel_launch(void* const* d_in, const int* in_sizes, int n_in,
                              void* d_out, int out_size, void* d_ws, size_t ws_size,
                              hipStream_t stream) {
    const float* x     = (const float*)d_in[0];
    const float* state = (const float*)d_in[1];
    const unsigned char* ns = (const unsigned char*)d_in[2];
    const int*   len   = (const int*)d_in[3];
    const float* tmx   = (const float*)d_in[4];
    const float* tmr   = (const float*)d_in[5];
    const float* tmk   = (const float*)d_in[6];
    const float* tmv   = (const float*)d_in[7];
    const float* tmw   = (const float*)d_in[8];
    const float* tmg   = (const float*)d_in[9];
    const float* W1    = (const float*)d_in[10];   // [C,160]
    const float* W2    = (const float*)d_in[11];   // [5,32,C]
    const float* tdec  = (const float*)d_in[12];   // [C]
    const float* Wd1   = (const float*)d_in[13];   // [C,64]
    const float* Wd2   = (const float*)d_in[14];   // [64,C]
    const float* Wq    = (const float*)d_in[15];
    const float* Wk    = (const float*)d_in[16];
    const float* Wv    = (const float*)d_in[17];
    const float* Wg    = (const float*)d_in[18];
    const float* Wo    = (const float*)d_in[19];

    float* out = (float*)d_out;
    float* outstate = out + (size_t)T_DIM * C_DIM;

    // ---- workspace layout (byte offsets; 122 MB total, aliased) ----
    // U is now 32 MB [H][NC=64][64][64] and spans the ENTIRE weight region
    // 90..122 MB: all WT buffers are dead before pass1 except WoT, whose
    // cast is deferred to after pass3 (when U is dead).
    char* wsb = (char*)d_ws;
    const size_t MB = 1024 * 1024;
    float*    sx   = (float*)(wsb + 0);            // 16 MB; later dec
    ushort_t* xxxb = (ushort_t*)(wsb + 16 * MB);   // 8 MB; later y0b
    ushort_t* mtlb = (ushort_t*)(wsb + 24 * MB);   // 1 MB  [T,256] bf16 tanh
    ushort_t* tw   = (ushort_t*)(wsb + 25 * MB);   // 0.5 MB [T,128] bf16
    float*    P    = (float*)(wsb + 25 * MB + 512 * 1024);  // 512 KB [H*NC*64]
    ushort_t* xr   = (ushort_t*)(wsb + 26 * MB);   // 8 MB
    ushort_t* xk   = (ushort_t*)(wsb + 34 * MB);   // 8 MB
    ushort_t* xv   = (ushort_t*)(wsb + 42 * MB);   // 8 MB
    ushort_t* xw   = (ushort_t*)(wsb + 50 * MB);   // 8 MB
    ushort_t* xg   = (ushort_t*)(wsb + 58 * MB);   // 8 MB  (ends 66)
    float*    g    = (float*)(wsb + 42 * MB);      // 16 MB over xv,xw
    float*    r    = (float*)(wsb + 66 * MB);      // 16 MB
    float*    k0   = (float*)(wsb + 82 * MB);      // 4 MB
    float*    v0   = (float*)(wsb + 86 * MB);      // 4 MB
    ushort_t* WqT  = (ushort_t*)(wsb + 90 * MB);   // 8 MB
    ushort_t* WkT  = (ushort_t*)(wsb + 98 * MB);   // 2 MB
    ushort_t* WvT  = (ushort_t*)(wsb + 100 * MB);  // 2 MB
    ushort_t* W1T  = (ushort_t*)(wsb + 102 * MB);  // 1 MB  [256,2048]
    ushort_t* Wd1T = (ushort_t*)(wsb + 103 * MB);  // 0.5 MB [128,2048]
    ushort_t* Wd2T = (ushort_t*)(wsb + 103 * MB + 512 * 1024); // 0.25 MB [2048,64]
    ushort_t* W2Tall = (ushort_t*)(wsb + 104 * MB); // 640 KB [5][C][32]
    ushort_t* WgT  = (ushort_t*)(wsb + 106 * MB);  // 8 MB
    ushort_t* WoT  = (ushort_t*)(wsb + 114 * MB);  // 8 MB (cast AFTER pass3)
    float*    U    = (float*)(wsb + 90 * MB);      // 32 MB over 90..122 (alive pass1..pass3)
    float*    dec  = sx;
    ushort_t* y0b  = xxxb;

    dim3 blk(256);
    int nElem4 = T_DIM * C_DIM / 4;

    // ---- weight cast+transpose (all but Wo; WoT region is U's tail) ----
    castT_kernel<<<dim3(8, 64), blk, 0, stream>>>(W1, W1T, 2048, 160);     // ->[256,2048]
    castT_kernel<<<dim3(4, 64), blk, 0, stream>>>(Wd1, Wd1T, 2048, 64);    // ->[128,2048]
    castT_kernel<<<dim3(64, 2), blk, 0, stream>>>(Wd2, Wd2T, 64, 2048);    // ->[2048,64]
    castT_kernel<<<dim3(64, 64), blk, 0, stream>>>(Wq, WqT, 2048, 2048);
    castT_kernel<<<dim3(16, 64), blk, 0, stream>>>(Wk, WkT, 2048, 512);
    castT_kernel<<<dim3(16, 64), blk, 0, stream>>>(Wv, WvT, 2048, 512);
    castT_kernel<<<dim3(64, 64), blk, 0, stream>>>(Wg, WgT, 2048, 2048);
    // W2 branches: [32,C] -> [C,32] bf16
    for (int br = 0; br < 5; ++br)
        castT_kernel<<<dim3(64, 1), blk, 0, stream>>>(
            W2 + (size_t)br * 32 * C_DIM, W2Tall + (size_t)br * C_DIM * 32, 32, 2048);

    // ---- prep / LoRA ----
    prep_kernel<<<dim3((nElem4 + 255) / 256), blk, 0, stream>>>(x, state, ns, tmx, sx, xxxb);
    gemm_mfma<4><<<dim3(2, 16), blk, 0, stream>>>(xxxb, 2048, W1T, nullptr, nullptr, mtlb, 256, 2048);
    maa_gemm<<<dim3(16, 16, 5), blk, 0, stream>>>(mtlb, W2Tall, x, sx,
                                                  tmr, tmk, tmv, tmw, tmg,
                                                  xr, xk, xv, xw, xg);
    // ---- projections (order matters for aliasing) ----
    gemm_mfma<4><<<dim3(1, 16), blk, 0, stream>>>(xw, 2048, Wd1T, nullptr, nullptr, tw, 128, 2048);
    gemm_mfma<0><<<dim3(4, 16), blk, 0, stream>>>(xk, 2048, WkT, nullptr, k0, nullptr, 512, 2048);
    gemm_mfma<0><<<dim3(4, 16), blk, 0, stream>>>(xv, 2048, WvT, nullptr, v0, nullptr, 512, 2048);
    gemm_mfma<0><<<dim3(16, 16), blk, 0, stream>>>(xr, 2048, WqT, nullptr, r, nullptr, 2048, 2048);
    gemm_mfma<3><<<dim3(16, 16), blk, 0, stream>>>(tw, 128, Wd2T, tdec, dec, nullptr, 2048, 64);
    gemm_mfma<2><<<dim3(16, 16), blk, 0, stream>>>(xg, 2048, WgT, nullptr, g, nullptr, 2048, 2048);
    // ---- chunked scan (weights in 90..122 now dead; U takes the region) ----
    scan_pass1<<<dim3(NH, NC), dim3(64), 0, stream>>>(k0, v0, dec, ns, U, P);
    scan_pass2<<<dim3(512), blk, 0, stream>>>(U, P, state, outstate);
    scan_pass3<<<dim3(NH, NC), dim3(64), 0, stream>>>(r, k0, v0, dec, ns, U, g, y0b);
    // ---- output (U dead -> cast Wo into its tail, then final GEMM) ----
    castT_kernel<<<dim3(64, 64), blk, 0, stream>>>(Wo, WoT, 2048, 2048);
    gemm_mfma<0><<<dim3(16, 16), blk, 0, stream>>>(y0b, 2048, WoT, nullptr, out, nullptr, 2048, 2048);
    state0_kernel<<<dim3(8), blk, 0, stream>>>(x, len, outstate);
}